// Round 6
// baseline (580.568 us; speedup 1.0000x reference)
//
#include <hip/hip_runtime.h>
#include <hip/hip_fp16.h>

// GCN 2-layer: 256 -> 16 -> 1, N=100000, E=3.2M + self loops.
//   out[d] = isq[d]*(sum_src ts[src] + ts[d]) + b2,  ts = (h2 @ W2)*isq
//   h2 = relu(isq[d]*(sum_src hs[src] + hs[d]) + b1), hs = (x @ W1)*isq
// R13: sort-free. k_p1 bins edges by super-bucket (256 nodes, dst>>8);
// aggregation streams the unsorted region, accumulating into LDS f32.
// R14: (a) f32 LDS accumulation via unsafeAtomicAdd -> native ds_add_f32.
//      R13's plain atomicAdd(float*) was lowered to a CAS LOOP (FP-safety
//      default): k_agg1f=341us, VALUBusy 1.5%, DS-conflicts 0 (the tell).
//      (b) k_p1 saves the phase-A atomic's return as the edge rank ->
//      second per-edge claim atomic deleted (LDS atomics 2/edge -> 1/edge).
// Swizzle in agg1f: slot = f ^ ((d>>1)&15), bank = 16*(d&1) + slot -> all
// 32 banks uniform for random d (~2-way, free per m136).

#define SBSH 8              // 256 nodes per super-bucket
#define SBCAP 10240         // region capacity (mean 8192, +22 sigma)
#define HPAD 400            // >= Bsb = ceil(N/256) = 391
#define GSTR 16             // gcur stride in ints (64B line each)
#define BINTHREADS 1024
#define ITEMS 8             // edges per thread in k_p1

__global__ void k_init(int* __restrict__ gcur, int Bsb) {
    int i = blockIdx.x * blockDim.x + threadIdx.x;
    if (i < Bsb) gcur[i * GSTR] = i * SBCAP;
}

// Pass 1: counting scatter into super-bucket regions. Per-block LDS histogram;
// phase-A atomic return value IS the edge's local rank (no re-claim pass).
__global__ __launch_bounds__(BINTHREADS) void k_p1(
    const int* __restrict__ src, const int* __restrict__ dst,
    int* __restrict__ gcur, int* __restrict__ pairs, int E, int Bsb)
{
    __shared__ int hist[HPAD];
    const int t = threadIdx.x;
    const int base4 = blockIdx.x * (BINTHREADS * ITEMS / 4);
    for (int i = t; i < HPAD; i += BINTHREADS) hist[i] = 0;
    __syncthreads();

    int4 dd[ITEMS / 4];
    int4 rk[ITEMS / 4];
    #pragma unroll
    for (int r = 0; r < ITEMS / 4; ++r) {
        const int i4 = base4 + r * BINTHREADS + t;
        const int i = i4 << 2;
        int4 v;
        if (i + 3 < E) v = ((const int4*)dst)[i4];
        else {
            v.x = (i     < E) ? dst[i]     : -1;
            v.y = (i + 1 < E) ? dst[i + 1] : -1;
            v.z = (i + 2 < E) ? dst[i + 2] : -1;
            v.w = (i + 3 < E) ? dst[i + 3] : -1;
        }
        dd[r] = v;
        int4 q = make_int4(0, 0, 0, 0);
        if (v.x >= 0) q.x = atomicAdd(&hist[v.x >> SBSH], 1);
        if (v.y >= 0) q.y = atomicAdd(&hist[v.y >> SBSH], 1);
        if (v.z >= 0) q.z = atomicAdd(&hist[v.z >> SBSH], 1);
        if (v.w >= 0) q.w = atomicAdd(&hist[v.w >> SBSH], 1);
        rk[r] = q;
    }
    __syncthreads();
    for (int i = t; i < Bsb; i += BINTHREADS) {
        int c = hist[i];
        hist[i] = c ? atomicAdd(&gcur[i * GSTR], c) : 0;  // bulk claim -> abs base
    }
    __syncthreads();
    #pragma unroll
    for (int r = 0; r < ITEMS / 4; ++r) {
        const int i4 = base4 + r * BINTHREADS + t;
        const int i = i4 << 2;
        int4 s;
        if (i + 3 < E) s = ((const int4*)src)[i4];
        else {
            s.x = (i     < E) ? src[i]     : 0;
            s.y = (i + 1 < E) ? src[i + 1] : 0;
            s.z = (i + 2 < E) ? src[i + 2] : 0;
            s.w = (i + 3 < E) ? src[i + 3] : 0;
        }
        int4 v = dd[r];
        int4 q = rk[r];
        if (v.x >= 0) pairs[hist[v.x >> SBSH] + q.x] = (s.x << SBSH) | (v.x & 255);
        if (v.y >= 0) pairs[hist[v.y >> SBSH] + q.y] = (s.y << SBSH) | (v.y & 255);
        if (v.z >= 0) pairs[hist[v.z >> SBSH] + q.z] = (s.z << SBSH) | (v.z & 255);
        if (v.w >= 0) pairs[hist[v.w >> SBSH] + q.w] = (s.w << SBSH) | (v.w & 255);
    }
}

// Degrees -> isq. Block per super-bucket: coalesced int4 region read,
// LDS hist-256 (native int ds_add), rsqrt(deg+1).
__global__ __launch_bounds__(1024) void k_deg(
    const int* __restrict__ pairs, const int* __restrict__ gcur,
    float* __restrict__ isq, int N)
{
    __shared__ int hist[256];
    const int t = threadIdx.x, sb = blockIdx.x;
    const int beg = sb * SBCAP;
    const int cnt = gcur[sb * GSTR] - beg;
    if (t < 256) hist[t] = 0;
    __syncthreads();
    const int c4 = cnt >> 2;
    const int4* p4 = (const int4*)(pairs + beg);
    for (int i = t; i < c4; i += 1024) {
        int4 v = p4[i];
        atomicAdd(&hist[v.x & 255], 1);
        atomicAdd(&hist[v.y & 255], 1);
        atomicAdd(&hist[v.z & 255], 1);
        atomicAdd(&hist[v.w & 255], 1);
    }
    for (int i = (c4 << 2) + t; i < cnt; i += 1024)
        atomicAdd(&hist[pairs[beg + i] & 255], 1);
    __syncthreads();
    if (t < 256) {
        const int n = (sb << SBSH) + t;
        if (n < N) isq[n] = rsqrtf((float)(hist[t] + 1));  // +1 self loop
    }
}

// hs16[n][f] = half( dot(x[n,:], W1[:,f]) * isq[n] ).
// 2-way K-split by wave; readfirstlane keeps W1 index wave-uniform -> s_load.
__global__ __launch_bounds__(256) void k_lin1(
    const float* __restrict__ x, const float* __restrict__ W1,
    const float* __restrict__ isq, __half* __restrict__ hs16, int N)
{
    __shared__ float part[128][16];
    const int t = threadIdx.x;
    const int w = t >> 6, lane = t & 63;
    const int hu = __builtin_amdgcn_readfirstlane(w >> 1);   // uniform half
    const int nl = ((w & 1) << 6) + lane;                    // 0..127
    const int n = blockIdx.x * 128 + nl;
    const int nc = (n < N) ? n : (N - 1);                    // clamped row
    const float4* xr = (const float4*)(x + ((size_t)nc << 8) + (hu << 7));
    float acc[16];
    #pragma unroll
    for (int f = 0; f < 16; ++f) acc[f] = 0.f;
    #pragma unroll 1
    for (int kb = 0; kb < 4; ++kb) {
        float4 xa[8];
        #pragma unroll
        for (int u = 0; u < 8; ++u) xa[u] = xr[(kb << 3) + u];   // 8 in flight
        #pragma unroll
        for (int u = 0; u < 8; ++u) {
            const int k4 = (kb << 3) + u;                        // 0..31
            const float4* wr = (const float4*)W1 + (hu << 9) + (k4 << 4);
            const float xv[4] = { xa[u].x, xa[u].y, xa[u].z, xa[u].w };
            #pragma unroll
            for (int j = 0; j < 4; ++j) {
                #pragma unroll
                for (int f4 = 0; f4 < 4; ++f4) {
                    const float4 wv = wr[(j << 2) + f4];         // uniform
                    acc[(f4 << 2) + 0] = fmaf(xv[j], wv.x, acc[(f4 << 2) + 0]);
                    acc[(f4 << 2) + 1] = fmaf(xv[j], wv.y, acc[(f4 << 2) + 1]);
                    acc[(f4 << 2) + 2] = fmaf(xv[j], wv.z, acc[(f4 << 2) + 2]);
                    acc[(f4 << 2) + 3] = fmaf(xv[j], wv.w, acc[(f4 << 2) + 3]);
                }
            }
        }
    }
    if (hu == 1) {                       // upper-half waves stage partials
        #pragma unroll
        for (int f4 = 0; f4 < 4; ++f4) {
            const int fs = (f4 ^ (nl & 3)) << 2;
            *(float4*)&part[nl][fs] =
                make_float4(acc[(f4 << 2) + 0], acc[(f4 << 2) + 1],
                            acc[(f4 << 2) + 2], acc[(f4 << 2) + 3]);
        }
    }
    __syncthreads();
    if (hu == 0 && n < N) {
        #pragma unroll
        for (int f4 = 0; f4 < 4; ++f4) {
            const int fs = (f4 ^ (nl & 3)) << 2;
            float4 p = *(const float4*)&part[nl][fs];
            acc[(f4 << 2) + 0] += p.x;
            acc[(f4 << 2) + 1] += p.y;
            acc[(f4 << 2) + 2] += p.z;
            acc[(f4 << 2) + 3] += p.w;
        }
        const float iq = isq[n];
        __half2* o = (__half2*)&hs16[(size_t)n << 4];
        #pragma unroll
        for (int f2 = 0; f2 < 8; ++f2)
            o[f2] = __floats2half2_rn(acc[2 * f2] * iq, acc[2 * f2 + 1] * iq);
    }
}

// Layer-1 aggregation, sort-free. Block per super-bucket: stream unsorted
// region; per edge gather 32B hs16[src] and ds_add_f32 (unsafeAtomicAdd)
// 16 features into facc[256][16], slot XOR-swizzled. Epilogue fuses
// self-loop + isq + b1 + relu + W2 + isq -> ts.
__global__ __launch_bounds__(1024) void k_agg1f(
    const int* __restrict__ pairs, const int* __restrict__ gcur,
    const __half* __restrict__ hs16, const float* __restrict__ isq,
    const float* __restrict__ b1, const float* __restrict__ W2,
    float* __restrict__ ts, int N)
{
    __shared__ float facc[256 * 16];     // 16KB
    const int t = threadIdx.x, sb = blockIdx.x;
    const int beg = sb * SBCAP;
    const int cnt = gcur[sb * GSTR] - beg;
    #pragma unroll
    for (int i = t; i < 4096; i += 1024) facc[i] = 0.f;
    __syncthreads();
    for (int i = t; i < cnt; i += 1024) {
        const int p = pairs[beg + i];
        const int s = p >> SBSH, d = p & 255;
        const int r = (d >> 1) & 15;
        float* fb = &facc[d << 4];
        union { float4 v; __half2 h[4]; } U0, U1;
        const float4* hr = (const float4*)(hs16 + ((size_t)s << 4));
        U0.v = hr[0];
        U1.v = hr[1];
        #pragma unroll
        for (int c = 0; c < 4; ++c) {
            float2 f2 = __half22float2(U0.h[c]);
            unsafeAtomicAdd(&fb[(2 * c)     ^ r], f2.x);
            unsafeAtomicAdd(&fb[(2 * c + 1) ^ r], f2.y);
        }
        #pragma unroll
        for (int c = 0; c < 4; ++c) {
            float2 f2 = __half22float2(U1.h[c]);
            unsafeAtomicAdd(&fb[(8 + 2 * c) ^ r], f2.x);
            unsafeAtomicAdd(&fb[(9 + 2 * c) ^ r], f2.y);
        }
    }
    __syncthreads();
    if (t < 256) {
        const int n = (sb << SBSH) + t;
        if (n < N) {
            const float iq = isq[n];
            const int r = (t >> 1) & 15;
            const float* fb = &facc[t << 4];
            union { float4 v; __half2 h[4]; } S0, S1;
            const float4* hr = (const float4*)(hs16 + ((size_t)n << 4));
            S0.v = hr[0];
            S1.v = hr[1];
            float acc = 0.f;
            #pragma unroll
            for (int c = 0; c < 4; ++c) {
                float2 sf = __half22float2(S0.h[c]);
                float a0 = fb[(2 * c)     ^ r] + sf.x;      // + self loop
                float a1 = fb[(2 * c + 1) ^ r] + sf.y;
                acc += fmaxf(a0 * iq + b1[2 * c],     0.f) * W2[2 * c]
                     + fmaxf(a1 * iq + b1[2 * c + 1], 0.f) * W2[2 * c + 1];
            }
            #pragma unroll
            for (int c = 0; c < 4; ++c) {
                float2 sf = __half22float2(S1.h[c]);
                float a0 = fb[(8 + 2 * c) ^ r] + sf.x;
                float a1 = fb[(9 + 2 * c) ^ r] + sf.y;
                acc += fmaxf(a0 * iq + b1[8 + 2 * c], 0.f) * W2[8 + 2 * c]
                     + fmaxf(a1 * iq + b1[9 + 2 * c], 0.f) * W2[9 + 2 * c];
            }
            ts[n] = acc * iq;
        }
    }
}

// Layer-2 aggregation, sort-free: sacc[256] f32, one native ds_add per edge,
// scalar ts gather (L2-resident).
__global__ __launch_bounds__(1024) void k_agg2f(
    const int* __restrict__ pairs, const int* __restrict__ gcur,
    const float* __restrict__ ts, const float* __restrict__ isq,
    const float* __restrict__ b2, float* __restrict__ out, int N)
{
    __shared__ float sacc[256];
    const int t = threadIdx.x, sb = blockIdx.x;
    const int beg = sb * SBCAP;
    const int cnt = gcur[sb * GSTR] - beg;
    if (t < 256) sacc[t] = 0.f;
    __syncthreads();
    for (int i = t; i < cnt; i += 1024) {
        const int p = pairs[beg + i];
        unsafeAtomicAdd(&sacc[p & 255], ts[p >> SBSH]);
    }
    __syncthreads();
    if (t < 256) {
        const int n = (sb << SBSH) + t;
        if (n < N) out[n] = (sacc[t] + ts[n]) * isq[n] + b2[0];
    }
}

extern "C" void kernel_launch(void* const* d_in, const int* in_sizes, int n_in,
                              void* d_out, int out_size, void* d_ws, size_t ws_size,
                              hipStream_t stream) {
    const float* x  = (const float*)d_in[0];
    const int*   ei = (const int*)d_in[1];
    const float* W1 = (const float*)d_in[2];
    const float* b1 = (const float*)d_in[3];
    const float* W2 = (const float*)d_in[4];
    const float* b2 = (const float*)d_in[5];
    const int N = in_sizes[0] / 256;
    const int E = in_sizes[1] / 2;
    const int* src = ei;
    const int* dst = ei + E;
    const int Bsb = (N + 255) >> SBSH;   // 391

    char* w = (char*)d_ws;
    float*  isq   = (float*)w;  w += (size_t)N * 4;
    int*    gcur  = (int*)w;    w += (size_t)HPAD * GSTR * 4;   // padded
    int*    pairs = (int*)w;    w += (size_t)Bsb * SBCAP * 4;   // 16.0 MB
    __half* hs16  = (__half*)w; w += (size_t)N * 32;            // 3.2 MB
    float*  ts    = (float*)w;  w += (size_t)N * 4;
    float*  out   = (float*)d_out;

    k_init<<<(Bsb + 255) / 256, 256, 0, stream>>>(gcur, Bsb);

    const int nbBin = (E + BINTHREADS * ITEMS - 1) / (BINTHREADS * ITEMS);  // 391
    k_p1<<<nbBin, BINTHREADS, 0, stream>>>(src, dst, gcur, pairs, E, Bsb);

    k_deg<<<Bsb, 1024, 0, stream>>>(pairs, gcur, isq, N);

    k_lin1<<<(N + 127) / 128, 256, 0, stream>>>(x, W1, isq, hs16, N);

    k_agg1f<<<Bsb, 1024, 0, stream>>>(pairs, gcur, hs16, isq, b1, W2, ts, N);
    k_agg2f<<<Bsb, 1024, 0, stream>>>(pairs, gcur, ts, isq, b2, out, N);
}

// Round 7
// 260.806 us; speedup vs baseline: 2.2261x; 2.2261x over previous
//
#include <hip/hip_runtime.h>
#include <hip/hip_fp16.h>

// GCN 2-layer: 256 -> 16 -> 1, N=100000, E=3.2M + self loops.
//   out[d] = isq[d]*(sum_src ts[src] + ts[d]) + b2,  ts = (h2 @ W2)*isq
//   h2 = relu(isq[d]*(sum_src hs[src] + hs[d]) + b1), hs = (x @ W1)*isq
// HW model learned R13/R14: LDS atomics ~1 lane-op/cy/CU (agg1f: 205M
// lane-atomics = 341us, identical with unsafeAtomicAdd -> was native
// ds_add_f32 all along; VALU/HBM/bank-conflict counters all ~idle).
// => minimize atomic COUNT, accumulate in registers, sorted-run design.
// R15: sorted pipeline with atomic/scatter dieting:
//  - k_p1: regs-only presort. count w/ rank-save (1 atomic/edge), scan-391,
//    LDS scatter (pack+runid), COALESCED run write-out (12.8M scattered
//    4B store-lines -> ~1.5M).
//  - k_sortsb: phase-1 atomic return saved as rank in unrolled reg arrays
//    (same i-mapping both phases) -> scatter pass has ZERO atomics; e[]
//    staging deleted (values live in regs).
//  - k_agg1/k_agg2: R12 register-accum 8-lane; k_lin1: R11 s_load W1.

#define SBSH 8              // 256 nodes per super-bucket
#define SBCAP 10240         // region capacity (mean 8192, +22 sigma)
#define LCAP 9216           // sortsb capacity (mean 8192, +11 sigma)
#define HPAD 400            // >= Bsb = ceil(N/256) = 391
#define GSTR 16             // gcur stride in ints (64B line each)
#define PEDG 8192           // edges per k_p1 block

__global__ void k_init(int* __restrict__ gcur, int Bsb) {
    int i = blockIdx.x * blockDim.x + threadIdx.x;
    if (i < Bsb) gcur[i * GSTR] = i * SBCAP;
}

// Pass 1: per-block presort by super-bucket, coalesced run write-out.
// Edges live in registers end-to-end; one LDS atomic per edge (rank-save).
__global__ __launch_bounds__(1024) void k_p1(
    const int* __restrict__ src, const int* __restrict__ dst,
    int* __restrict__ gcur, int* __restrict__ pairs, int E, int Bsb)
{
    __shared__ int s2[PEDG];                 // 32KB packed, sorted by sb
    __shared__ unsigned short rid[PEDG];     // 16KB run-id per slot
    __shared__ int hist[392];
    __shared__ int loc[392];
    __shared__ int gbase[392];
    __shared__ int wsum[8];
    const int t = threadIdx.x;
    const int base4 = blockIdx.x * (PEDG / 4);
    for (int i = t; i < 392; i += 1024) hist[i] = 0;
    __syncthreads();

    int4 dd[2], ss[2], rk[2];
    #pragma unroll
    for (int r = 0; r < 2; ++r) {
        const int i4 = base4 + r * 1024 + t;
        const int i = i4 << 2;
        int4 v, s;
        if (i + 3 < E) {
            v = ((const int4*)dst)[i4];
            s = ((const int4*)src)[i4];
        } else {
            v.x = (i     < E) ? dst[i]     : -1;
            v.y = (i + 1 < E) ? dst[i + 1] : -1;
            v.z = (i + 2 < E) ? dst[i + 2] : -1;
            v.w = (i + 3 < E) ? dst[i + 3] : -1;
            s.x = (i     < E) ? src[i]     : 0;
            s.y = (i + 1 < E) ? src[i + 1] : 0;
            s.z = (i + 2 < E) ? src[i + 2] : 0;
            s.w = (i + 3 < E) ? src[i + 3] : 0;
        }
        dd[r] = v; ss[r] = s;
        int4 q = make_int4(0, 0, 0, 0);
        if (v.x >= 0) q.x = atomicAdd(&hist[v.x >> SBSH], 1);
        if (v.y >= 0) q.y = atomicAdd(&hist[v.y >> SBSH], 1);
        if (v.z >= 0) q.z = atomicAdd(&hist[v.z >> SBSH], 1);
        if (v.w >= 0) q.w = atomicAdd(&hist[v.w >> SBSH], 1);
        rk[r] = q;
    }
    __syncthreads();
    int c = 0, vv = 0;
    if (t < 391) {                           // scan of 391 counts (7 waves)
        const int lane = t & 63, w = t >> 6;
        c = hist[t];
        vv = c;
        #pragma unroll
        for (int off = 1; off < 64; off <<= 1) {
            int u = __shfl_up(vv, off, 64);
            if (lane >= off) vv += u;
        }
        if (lane == 63 || t == 390) wsum[w] = vv;
    }
    __syncthreads();
    if (t < 391) {
        const int w = t >> 6;
        int add = 0;
        #pragma unroll
        for (int i = 0; i < 6; ++i) if (i < w) add += wsum[i];
        int inc = vv + add, exc = inc - c;
        loc[t] = exc;
        if (t == 390) loc[391] = inc;        // total valid edges this block
        gbase[t] = c ? atomicAdd(&gcur[t * GSTR], c) : 0;  // bulk claim
    }
    __syncthreads();
    const int tot = loc[391];
    #pragma unroll
    for (int r = 0; r < 2; ++r) {            // LDS scatter from registers
        int4 v = dd[r], s = ss[r], q = rk[r];
        if (v.x >= 0) { int sb = v.x >> SBSH; int p = loc[sb] + q.x; s2[p] = (s.x << SBSH) | (v.x & 255); rid[p] = (unsigned short)sb; }
        if (v.y >= 0) { int sb = v.y >> SBSH; int p = loc[sb] + q.y; s2[p] = (s.y << SBSH) | (v.y & 255); rid[p] = (unsigned short)sb; }
        if (v.z >= 0) { int sb = v.z >> SBSH; int p = loc[sb] + q.z; s2[p] = (s.z << SBSH) | (v.z & 255); rid[p] = (unsigned short)sb; }
        if (v.w >= 0) { int sb = v.w >> SBSH; int p = loc[sb] + q.w; s2[p] = (s.w << SBSH) | (v.w & 255); rid[p] = (unsigned short)sb; }
    }
    __syncthreads();
    for (int i = t; i < tot; i += 1024) {    // coalesced-per-run write-out
        const int sb = rid[i];
        pairs[gbase[sb] + (i - loc[sb])] = s2[i];
    }
}

// Pass 2: per-super-bucket counting sort by 8-bit local dst.
// Rank-save: phase-1 atomic returns are the scatter ranks (reg arrays,
// identical i-mapping). No e[] staging, no scatter atomics.
__global__ __launch_bounds__(1024) void k_sortsb(
    int* __restrict__ pairs, const int* __restrict__ gcur,
    int* __restrict__ rowp, float* __restrict__ isq, int N)
{
    __shared__ int s2[LCAP];             // 36KB sorted srcs
    __shared__ int hist[256];
    __shared__ int exc[256];
    __shared__ int wsum[4];
    const int t = threadIdx.x, sb = blockIdx.x;
    const int beg = sb * SBCAP;
    int cnt = gcur[sb * GSTR] - beg;
    if (cnt > LCAP) cnt = LCAP;          // +11 sigma, statistically never
    if (t < 256) hist[t] = 0;
    __syncthreads();
    const int c4 = cnt >> 2;
    const int4* p4 = (const int4*)(pairs + beg);
    int4 va[3], ra[3];
    int vr = 0, rr = 0;
    #pragma unroll
    for (int k = 0; k < 3; ++k) {        // c4 <= 2304 -> 3 iters max
        const int i = t + k * 1024;
        if (i < c4) {
            int4 v = p4[i];
            va[k] = v;
            ra[k].x = atomicAdd(&hist[v.x & 255], 1);
            ra[k].y = atomicAdd(&hist[v.y & 255], 1);
            ra[k].z = atomicAdd(&hist[v.z & 255], 1);
            ra[k].w = atomicAdd(&hist[v.w & 255], 1);
        }
    }
    {
        const int i = (c4 << 2) + t;
        if (i < cnt) { vr = pairs[beg + i]; rr = atomicAdd(&hist[vr & 255], 1); }
    }
    __syncthreads();
    int c = 0, v = 0;
    if (t < 256) {                       // 4-wave scan of 256 counts
        const int lane = t & 63, w = t >> 6;
        c = hist[t];
        v = c;
        #pragma unroll
        for (int off = 1; off < 64; off <<= 1) {
            int u = __shfl_up(v, off, 64);
            if (lane >= off) v += u;
        }
        if (lane == 63) wsum[w] = v;
    }
    __syncthreads();
    if (t < 256) {
        const int w = t >> 6;
        int add = 0;
        #pragma unroll
        for (int i = 0; i < 3; ++i) if (i < w) add += wsum[i];
        int inc = v + add;               // inclusive prefix
        int e0 = inc - c;
        exc[t] = e0;
        rowp[sb * 257 + t] = e0;
        if (t == 255) rowp[sb * 257 + 256] = inc;   // == cnt
        int n = (sb << SBSH) + t;
        if (n < N) isq[n] = rsqrtf((float)(c + 1)); // +1 self loop
    }
    __syncthreads();
    #pragma unroll
    for (int k = 0; k < 3; ++k) {        // scatter: exc[key] + saved rank
        const int i = t + k * 1024;
        if (i < c4) {
            int4 v2 = va[k], q = ra[k];
            s2[exc[v2.x & 255] + q.x] = v2.x >> SBSH;
            s2[exc[v2.y & 255] + q.y] = v2.y >> SBSH;
            s2[exc[v2.z & 255] + q.z] = v2.z >> SBSH;
            s2[exc[v2.w & 255] + q.w] = v2.w >> SBSH;
        }
    }
    {
        const int i = (c4 << 2) + t;
        if (i < cnt) s2[exc[vr & 255] + rr] = vr >> SBSH;
    }
    __syncthreads();
    {
        int4* pw = (int4*)(pairs + beg);
        const int4* s4 = (const int4*)s2;
        for (int i = t; i < c4; i += 1024) pw[i] = s4[i];      // coalesced
        for (int i = (c4 << 2) + t; i < cnt; i += 1024) pairs[beg + i] = s2[i];
    }
}

// hs16[n][f] = half( dot(x[n,:], W1[:,f]) * isq[n] ).
// 2-way K-split by wave; readfirstlane keeps W1 index wave-uniform -> s_load.
__global__ __launch_bounds__(256) void k_lin1(
    const float* __restrict__ x, const float* __restrict__ W1,
    const float* __restrict__ isq, __half* __restrict__ hs16, int N)
{
    __shared__ float part[128][16];
    const int t = threadIdx.x;
    const int w = t >> 6, lane = t & 63;
    const int hu = __builtin_amdgcn_readfirstlane(w >> 1);   // uniform half
    const int nl = ((w & 1) << 6) + lane;                    // 0..127
    const int n = blockIdx.x * 128 + nl;
    const int nc = (n < N) ? n : (N - 1);                    // clamped row
    const float4* xr = (const float4*)(x + ((size_t)nc << 8) + (hu << 7));
    float acc[16];
    #pragma unroll
    for (int f = 0; f < 16; ++f) acc[f] = 0.f;
    #pragma unroll 1
    for (int kb = 0; kb < 4; ++kb) {
        float4 xa[8];
        #pragma unroll
        for (int u = 0; u < 8; ++u) xa[u] = xr[(kb << 3) + u];   // 8 in flight
        #pragma unroll
        for (int u = 0; u < 8; ++u) {
            const int k4 = (kb << 3) + u;                        // 0..31
            const float4* wr = (const float4*)W1 + (hu << 9) + (k4 << 4);
            const float xv[4] = { xa[u].x, xa[u].y, xa[u].z, xa[u].w };
            #pragma unroll
            for (int j = 0; j < 4; ++j) {
                #pragma unroll
                for (int f4 = 0; f4 < 4; ++f4) {
                    const float4 wv = wr[(j << 2) + f4];         // uniform
                    acc[(f4 << 2) + 0] = fmaf(xv[j], wv.x, acc[(f4 << 2) + 0]);
                    acc[(f4 << 2) + 1] = fmaf(xv[j], wv.y, acc[(f4 << 2) + 1]);
                    acc[(f4 << 2) + 2] = fmaf(xv[j], wv.z, acc[(f4 << 2) + 2]);
                    acc[(f4 << 2) + 3] = fmaf(xv[j], wv.w, acc[(f4 << 2) + 3]);
                }
            }
        }
    }
    if (hu == 1) {                       // upper-half waves stage partials
        #pragma unroll
        for (int f4 = 0; f4 < 4; ++f4) {
            const int fs = (f4 ^ (nl & 3)) << 2;
            *(float4*)&part[nl][fs] =
                make_float4(acc[(f4 << 2) + 0], acc[(f4 << 2) + 1],
                            acc[(f4 << 2) + 2], acc[(f4 << 2) + 3]);
        }
    }
    __syncthreads();
    if (hu == 0 && n < N) {
        #pragma unroll
        for (int f4 = 0; f4 < 4; ++f4) {
            const int fs = (f4 ^ (nl & 3)) << 2;
            float4 p = *(const float4*)&part[nl][fs];
            acc[(f4 << 2) + 0] += p.x;
            acc[(f4 << 2) + 1] += p.y;
            acc[(f4 << 2) + 2] += p.z;
            acc[(f4 << 2) + 3] += p.w;
        }
        const float iq = isq[n];
        __half2* o = (__half2*)&hs16[(size_t)n << 4];
        #pragma unroll
        for (int f2 = 0; f2 < 8; ++f2)
            o[f2] = __floats2half2_rn(acc[2 * f2] * iq, acc[2 * f2 + 1] * iq);
    }
}

// Layer-1 aggregation: 8 lanes/node = 4 feature-lanes x 2 run-parity lanes.
// Register accumulation, zero atomics; fused relu/W2/isq epilogue.
__global__ __launch_bounds__(256) void k_agg1(
    const int* __restrict__ sorted, const int* __restrict__ rowp,
    const __half* __restrict__ hs16, const float* __restrict__ isq,
    const float* __restrict__ b1, const float* __restrict__ W2,
    float* __restrict__ ts, int N)
{
    const int t = threadIdx.x, g = blockIdx.x;
    const int l = t >> 3, q = t & 3, p = (t >> 2) & 1;
    const int n = g * 32 + l;
    if (n >= N) return;
    const int sb = n >> SBSH, L = n & 255;
    const int rbeg = sb * SBCAP + rowp[sb * 257 + L];
    const int rend = sb * SBCAP + rowp[sb * 257 + L + 1];
    const float2* h2 = (const float2*)hs16;
    float a0 = 0.f, a1 = 0.f, a2 = 0.f, a3 = 0.f;
    for (int j = rbeg + p; j < rend; j += 2) {
        int s0 = sorted[j];
        float2 ra = h2[s0 * 4 + q];
        union { float f; __half2 h; } ca0, ca1;
        ca0.f = ra.x; ca1.f = ra.y;
        float2 fa0 = __half22float2(ca0.h), fa1 = __half22float2(ca1.h);
        a0 += fa0.x; a1 += fa0.y; a2 += fa1.x; a3 += fa1.y;
    }
    a0 += __shfl_xor(a0, 4);
    a1 += __shfl_xor(a1, 4);
    a2 += __shfl_xor(a2, 4);
    a3 += __shfl_xor(a3, 4);
    {   // self loop (post-combine: both parity lanes hold the full sum)
        float2 rs = h2[(size_t)n * 4 + q];
        union { float f; __half2 h; } c0, c1;
        c0.f = rs.x; c1.f = rs.y;
        float2 f0 = __half22float2(c0.h), f1 = __half22float2(c1.h);
        a0 += f0.x; a1 += f0.y; a2 += f1.x; a3 += f1.y;
    }
    const float iq = isq[n];
    const int f0i = q * 4;
    float pr = fmaxf(a0 * iq + b1[f0i + 0], 0.f) * W2[f0i + 0]
             + fmaxf(a1 * iq + b1[f0i + 1], 0.f) * W2[f0i + 1]
             + fmaxf(a2 * iq + b1[f0i + 2], 0.f) * W2[f0i + 2]
             + fmaxf(a3 * iq + b1[f0i + 3], 0.f) * W2[f0i + 3];
    pr += __shfl_xor(pr, 1);
    pr += __shfl_xor(pr, 2);
    if ((t & 7) == 0) ts[n] = pr * iq;
}

// Layer-2: 8 lanes/node striding the run, shfl reduce. Zero atomics.
__global__ __launch_bounds__(256) void k_agg2(
    const int* __restrict__ sorted, const int* __restrict__ rowp,
    const float* __restrict__ ts, const float* __restrict__ isq,
    const float* __restrict__ b2, float* __restrict__ out, int N)
{
    const int t = threadIdx.x;
    const int l = t >> 3, q = t & 7;
    const int n = blockIdx.x * 32 + l;
    if (n >= N) return;
    const int sb = n >> SBSH, L = n & 255;
    const int rbeg = sb * SBCAP + rowp[sb * 257 + L];
    const int rend = sb * SBCAP + rowp[sb * 257 + L + 1];
    float acc = 0.f;
    for (int j = rbeg + q; j < rend; j += 8) acc += ts[sorted[j]];
    acc += __shfl_xor(acc, 1);
    acc += __shfl_xor(acc, 2);
    acc += __shfl_xor(acc, 4);
    if (q == 0) out[n] = (acc + ts[n]) * isq[n] + b2[0];
}

extern "C" void kernel_launch(void* const* d_in, const int* in_sizes, int n_in,
                              void* d_out, int out_size, void* d_ws, size_t ws_size,
                              hipStream_t stream) {
    const float* x  = (const float*)d_in[0];
    const int*   ei = (const int*)d_in[1];
    const float* W1 = (const float*)d_in[2];
    const float* b1 = (const float*)d_in[3];
    const float* W2 = (const float*)d_in[4];
    const float* b2 = (const float*)d_in[5];
    const int N = in_sizes[0] / 256;
    const int E = in_sizes[1] / 2;
    const int* src = ei;
    const int* dst = ei + E;
    const int Bsb = (N + 255) >> SBSH;   // 391

    char* w = (char*)d_ws;
    float*  isq   = (float*)w;  w += (size_t)N * 4;
    int*    gcur  = (int*)w;    w += (size_t)HPAD * GSTR * 4;   // padded
    int*    pairs = (int*)w;    w += (size_t)Bsb * SBCAP * 4;   // 16.0 MB
    int*    rowp  = (int*)w;    w += (size_t)Bsb * 257 * 4;     // 402 KB
    __half* hs16  = (__half*)w; w += (size_t)N * 32;            // 3.2 MB
    float*  ts    = (float*)w;  w += (size_t)N * 4;
    float*  out   = (float*)d_out;

    k_init<<<(Bsb + 255) / 256, 256, 0, stream>>>(gcur, Bsb);

    const int nbBin = (E + PEDG - 1) / PEDG;   // 391
    k_p1<<<nbBin, 1024, 0, stream>>>(src, dst, gcur, pairs, E, Bsb);

    k_sortsb<<<Bsb, 1024, 0, stream>>>(pairs, gcur, rowp, isq, N);

    k_lin1<<<(N + 127) / 128, 256, 0, stream>>>(x, W1, isq, hs16, N);

    k_agg1<<<(N + 31) / 32, 256, 0, stream>>>(pairs, rowp, hs16, isq, b1, W2, ts, N);
    k_agg2<<<(N + 31) / 32, 256, 0, stream>>>(pairs, rowp, ts, isq, b2, out, N);
}